// Round 19
// baseline (75.182 us; speedup 1.0000x reference)
//
#include <hip/hip_runtime.h>

#define THREADS 256
#define DIN 60
#define HN 256
#define DOUT 360

typedef __attribute__((ext_vector_type(8))) short short8;
typedef __attribute__((ext_vector_type(16))) float f32x16;
typedef __attribute__((ext_vector_type(4))) float f32x4;
typedef __attribute__((ext_vector_type(4))) unsigned int u32x4;

// d_ws layout (bytes); total 229376 B
#define WS_CBF   0            // 2048 * 16 B = 32768  (ns-scaled centres + fold, [row][p], p=c^(row&7))
#define WS_W2    32768        // [row 0..383][pc 0..31] short8, pc=c^(row&31) = 196608 B

__device__ __forceinline__ short bf16_bits(float f) {   // prep-side only
    union { float f; unsigned u; } v; v.f = f;
    unsigned r = (v.u + 0x7FFFu + ((v.u >> 16) & 1u)) >> 16;
    return (short)(unsigned short)r;
}

__device__ __forceinline__ unsigned pk_bf16(float a, float b) {
    unsigned r;
    asm("v_cvt_pk_bf16_f32 %0, %1, %2" : "=v"(r) : "v"(a), "v"(b));
    return r;   // low16 = bf16(a), high16 = bf16(b)
}

__device__ __forceinline__ void gload16(const void* g, void* lds) {
    __builtin_amdgcn_global_load_lds(
        (const __attribute__((address_space(1))) unsigned int*)(uintptr_t)g,
        (__attribute__((address_space(3))) unsigned int*)(unsigned int)(uintptr_t)lds,
        16, 0, 0);
}

// ---------------- prep: convert/permute constants into ws (r16 verbatim) ----------------
__global__ void prep(const float* __restrict__ centres, const float* __restrict__ sigmas,
                     const float* __restrict__ W2, short* __restrict__ ws)
{
    int t = blockIdx.x * 256 + threadIdx.x;
    if (t < 12288) {
        int row = t >> 5, pc = t & 31;
        int c = pc ^ (row & 31);
        short8 v = {0,0,0,0,0,0,0,0};
        if (row < DOUT) {
            int rr = row / 12, jj = row % 12;
            int fcl = rr / 3, kk = rr % 3;
            int o = fcl * 36 + jj * 3 + kk;            // fold output col permutation
            const float* src = W2 + o * HN + c * 8;
            #pragma unroll
            for (int i = 0; i < 8; ++i) v[i] = bf16_bits(src[i]);
        }
        *(short8*)(ws + (WS_W2 / 2) + t * 8) = v;
    } else if (t < 14336) {
        // cbf (ns-fold): k<60: nsq*c_k ; k=60,61: hi/lo of -0.5*nsq*c2 (B=1,1) ;
        //                k=62,63: -0.5*nsq (B=x2hi,x2lo)
        int j = t - 12288;
        int row = j >> 3, p = j & 7;
        int c = p ^ (row & 7);
        const float* cr = centres + row * DIN;
        float sg = sigmas[row];
        union { unsigned u; float f; } nq;
        nq.u = ((unsigned)(unsigned short)bf16_bits(2.f * sg * sg * 1.44269504088896340736f)) << 16;
        const float nsq = nq.f;                        // bf16-exact
        short8 v = {0,0,0,0,0,0,0,0};
        if (c < 7) {
            #pragma unroll
            for (int i = 0; i < 8; ++i) {
                int k = c * 8 + i;
                if (k < DIN) v[i] = bf16_bits(nsq * cr[k]);
            }
        } else {   // k = 56..63
            #pragma unroll
            for (int i = 0; i < 4; ++i) v[i] = bf16_bits(nsq * cr[56 + i]);
            float c2 = 0.f;
            #pragma unroll
            for (int d = 0; d < DIN; ++d) c2 = fmaf(cr[d], cr[d], c2);
            float T = -0.5f * nsq * c2;
            union { unsigned u; float f; } th;
            th.u = ((unsigned)(unsigned short)bf16_bits(T)) << 16;   // T_hi (bf16-exact)
            v[4] = bf16_bits(th.f);
            v[5] = bf16_bits(T - th.f);
            v[6] = bf16_bits(-0.5f * nsq);
            v[7] = v[6];
        }
        *(short8*)(ws + (WS_CBF / 2) + j * 8) = v;
    }
}

// ---- one 32-row x tile -> fold-packed bf16 B-fragments (r12-verified layout) ----
__device__ __forceinline__ void load_xtile(const float* __restrict__ x, int row0,
                                           int l31, int hi, short8 xb[4]) {
    const float* xr = x + (size_t)(row0 + l31) * DIN;
    f32x4 xa[4][2];
    #pragma unroll
    for (int kt = 0; kt < 4; ++kt) {
        int k0 = kt * 16 + hi * 8;
        xa[kt][0] = *(const f32x4*)(xr + k0);
        xa[kt][1] = (k0 + 4 < DIN) ? *(const f32x4*)(xr + k0 + 4) : (f32x4){0.f,0.f,0.f,0.f};
    }
    float p2 = 0.f;
    #pragma unroll
    for (int kt = 0; kt < 4; ++kt)
        #pragma unroll
        for (int h = 0; h < 2; ++h)
            #pragma unroll
            for (int i = 0; i < 4; ++i) p2 = fmaf(xa[kt][h][i], xa[kt][h][i], p2);
    float x2v = p2 + __shfl_xor(p2, 32);
    union { unsigned u; float f; } hb; hb.u = pk_bf16(x2v, 0.f) << 16;  // x2hi (bf16-exact)
    float x2lo = x2v - hb.f;
    #pragma unroll
    for (int kt = 0; kt < 4; ++kt) {
        union { u32x4 u; short8 s; } a;
        a.u[0] = pk_bf16(xa[kt][0][0], xa[kt][0][1]);
        a.u[1] = pk_bf16(xa[kt][0][2], xa[kt][0][3]);
        a.u[2] = pk_bf16(xa[kt][1][0], xa[kt][1][1]);
        a.u[3] = pk_bf16(xa[kt][1][2], xa[kt][1][3]);
        if (kt == 3) {   // hi lanes: k=60..63 -> B = {1, 1, x2hi, x2lo}
            a.u[2] = hi ? 0x3F803F80u : a.u[2];
            a.u[3] = hi ? pk_bf16(hb.f, x2lo) : a.u[3];
        }
        xb[kt] = a.s;
    }
}

// --- main: 256 thr (1 wave/SIMD, 512-VGPR budget), fused + 2-tile paired LDS reads ---
__global__ __launch_bounds__(THREADS, 1)
void rbf_main(const float* __restrict__ x, const short* __restrict__ ws,
              float* __restrict__ out)
{
    __shared__ short8 w2h[6144];     // 96 KB: 192 rows x 32 chunks (this col-half)
    __shared__ short8 cbf[2048];     // 32 KB: ns-scaled centres + fold

    const int tid  = threadIdx.x;
    const int w    = tid >> 6;       // wave 0..3
    const int lane = tid & 63;
    const int l31  = lane & 31;
    const int hi   = lane >> 5;
    const int bid  = blockIdx.x;
    // XCD pair-swizzle (r12): bid and bid^8 share rows, differ in col-half
    const int f     = (bid >> 3) & 1;
    const int sbase = (bid & 7) | ((bid >> 4) << 3);   // 0..127, bijective

    // ---- stage everything once (async DMA), one barrier total ----
    #pragma unroll
    for (int i = 0; i < 24; ++i)
        gload16(ws + (WS_W2 / 2) + ((size_t)f * 6144 + i * THREADS + tid) * 8,
                (char*)w2h + (i * THREADS + tid) * 16);
    #pragma unroll
    for (int i = 0; i < 8; ++i)
        gload16(ws + (WS_CBF / 2) + (i * THREADS + tid) * 8, (char*)cbf + (i * THREADS + tid) * 16);

    // ---- iter-0 x (both tiles) before the barrier ----
    short8 xb0[4], xb1[4];
    load_xtile(x, sbase * 1024 + w * 64,      l31, hi, xb0);
    load_xtile(x, sbase * 1024 + w * 64 + 32, l31, hi, xb1);

    __syncthreads();   // LDS resident; no barriers, no LDS writes after this

    for (int it = 0; it < 4; ++it) {
        const int rb = sbase * 1024 + it * 256 + w * 64;

        f32x16 acc2[2][6];
        #pragma unroll
        for (int t = 0; t < 2; ++t)
            #pragma unroll
            for (int nt = 0; nt < 6; ++nt) acc2[t][nt] = (f32x16){};

        // ---- fused h-sweep: 8 chunks of 32 h; every LDS read feeds BOTH tiles ----
        #pragma unroll
        for (int nt1 = 0; nt1 < 8; ++nt1) {
            f32x16 a10 = (f32x16){}, a11 = (f32x16){};
            const int row = nt1 * 32 + l31;
            #pragma unroll
            for (int kt = 0; kt < 4; ++kt) {
                short8 cf = cbf[row * 8 + ((kt * 2 + hi) ^ (row & 7))];
                a10 = __builtin_amdgcn_mfma_f32_32x32x16_bf16(cf, xb0[kt], a10, 0, 0, 0);
                a11 = __builtin_amdgcn_mfma_f32_32x32x16_bf16(cf, xb1[kt], a11, 0, 0, 0);
            }

            unsigned pwl0[4][2], pwl1[4][2];
            #pragma unroll
            for (int q = 0; q < 4; ++q) {
                float p0[4], p1[4];
                #pragma unroll
                for (int j = 0; j < 4; ++j) {
                    p0[j] = exp2f(fminf(a10[4 * q + j], 0.f));
                    p1[j] = exp2f(fminf(a11[4 * q + j], 0.f));
                }
                pwl0[q][0] = pk_bf16(p0[0], p0[1]);
                pwl0[q][1] = pk_bf16(p0[2], p0[3]);
                pwl1[q][0] = pk_bf16(p1[0], p1[1]);
                pwl1[q][1] = pk_bf16(p1[2], p1[3]);
            }

            // 2 GEMM2 k-steps; wf reads shared across tiles (r12-verified permlane dir)
            #pragma unroll
            for (int m = 0; m < 2; ++m) {
                unsigned d00 = pwl0[2 * m][0], s00 = pwl0[2 * m + 1][0];
                unsigned d01 = pwl0[2 * m][1], s01 = pwl0[2 * m + 1][1];
                asm("v_permlane32_swap_b32 %0, %1" : "+v"(d00), "+v"(s00));
                asm("v_permlane32_swap_b32 %0, %1" : "+v"(d01), "+v"(s01));
                unsigned d10 = pwl1[2 * m][0], s10 = pwl1[2 * m + 1][0];
                unsigned d11 = pwl1[2 * m][1], s11 = pwl1[2 * m + 1][1];
                asm("v_permlane32_swap_b32 %0, %1" : "+v"(d10), "+v"(s10));
                asm("v_permlane32_swap_b32 %0, %1" : "+v"(d11), "+v"(s11));
                union { u32x4 u; short8 s; } b0, b1;
                b0.u[0] = d00; b0.u[1] = d01; b0.u[2] = s00; b0.u[3] = s01;
                b1.u[0] = d10; b1.u[1] = d11; b1.u[2] = s10; b1.u[3] = s11;
                const int ktg = nt1 * 2 + m;

                #pragma unroll
                for (int nt = 0; nt < 6; ++nt) {
                    int lrow = nt * 32 + l31;
                    short8 wf = w2h[lrow * 32 + ((ktg * 2 + hi) ^ l31)];
                    acc2[0][nt] = __builtin_amdgcn_mfma_f32_32x32x16_bf16(wf, b0.s, acc2[0][nt], 0, 0, 0);
                    acc2[1][nt] = __builtin_amdgcn_mfma_f32_32x32x16_bf16(wf, b1.s, acc2[1][nt], 0, 0, 0);
                }
            }
        }

        // ---- next iter's x (issued before stores) ----
        if (it < 3) {
            load_xtile(x, rb + 256,      l31, hi, xb0);
            load_xtile(x, rb + 256 + 32, l31, hi, xb1);
        }

        // ---- stores (r12-verified pattern) ----
        #pragma unroll
        for (int t = 0; t < 2; ++t) {
            float* op = out + (size_t)(rb + t * 32 + l31) * DOUT;
            #pragma unroll
            for (int nt = 0; nt < 6; ++nt) {
                #pragma unroll
                for (int q = 0; q < 4; ++q) {
                    int col = f * 192 + nt * 32 + q * 8 + hi * 4;
                    if (col < DOUT) {
                        f32x4 v;
                        v[0] = acc2[t][nt][4 * q + 0]; v[1] = acc2[t][nt][4 * q + 1];
                        v[2] = acc2[t][nt][4 * q + 2]; v[3] = acc2[t][nt][4 * q + 3];
                        *(f32x4*)(op + col) = v;
                    }
                }
            }
        }
    }
}

extern "C" void kernel_launch(void* const* d_in, const int* in_sizes, int n_in,
                              void* d_out, int out_size, void* d_ws, size_t ws_size,
                              hipStream_t stream) {
    const float* x       = (const float*)d_in[0];
    const float* centres = (const float*)d_in[1];
    const float* sigmas  = (const float*)d_in[2];
    const float* W2      = (const float*)d_in[3];
    float* out = (float*)d_out;
    short* ws  = (short*)d_ws;                  // needs 229376 B
    prep<<<dim3(56), dim3(256), 0, stream>>>(centres, sigmas, W2, ws);
    rbf_main<<<dim3(256), dim3(THREADS), 0, stream>>>(x, ws, out);
}